// Round 10
// baseline (161.164 us; speedup 1.0000x reference)
//
#include <hip/hip_runtime.h>

// ---- vector types (ext_vector for [] indexing; avoid HIP name collisions) ----
typedef __attribute__((ext_vector_type(8))) short short8v;      // 8 bf16 (4 VGPR) MFMA frag
typedef __attribute__((ext_vector_type(4))) float floatx4;      // MFMA accum
typedef __attribute__((ext_vector_type(4))) unsigned short ushortx4;

// RNE f32->bf16, 3 VALU ops (values are finite; no NaN path needed)
__device__ __forceinline__ unsigned int f2bf(float f){
  unsigned int u = __float_as_uint(f);
  u += 0x7fffu + ((u >> 16) & 1u);
  return u >> 16;
}

__device__ __forceinline__ void gload_lds16(const void* g, void* l){
  __builtin_amdgcn_global_load_lds((const __attribute__((address_space(1))) void*)g,
                                   (__attribute__((address_space(3))) void*)l, 16, 0, 0);
}

// ---- fused prep: f32->bf16 for tensor/w_qkv/w_proj + RoPE cos/sin table ----
// region boundaries are multiples of 256 -> each block is branch-uniform.
__global__ __launch_bounds__(256) void prep(
    const floatx4* __restrict__ t,  ushortx4* __restrict__ dt,
    const floatx4* __restrict__ wq, ushortx4* __restrict__ dq,
    const floatx4* __restrict__ wp, ushortx4* __restrict__ dp,
    float2* __restrict__ cs)
{
  int i = blockIdx.x * 256 + threadIdx.x;
  if(i < 3145728){
    const floatx4* s; ushortx4* d; int j;
    if(i < 2097152){ s = t;  d = dt; j = i; }
    else if(i < 2883584){ s = wq; d = dq; j = i - 2097152; }
    else { s = wp; d = dp; j = i - 2883584; }
    floatx4 v = s[j];
    ushortx4 o;
    #pragma unroll
    for(int k = 0; k < 4; ++k) o[k] = (unsigned short)f2bf(v[k]);
    d[j] = o;
  } else {
    int j = i - 3145728;              // 0..65535
    int p = j >> 6, dd = j & 63;
    int y = p >> 5, x = p & 31;
    int dm = dd & 31;
    float ifr = powf(10000.0f, -(float)dm * (1.0f / 32.0f));
    float th = (float)(dd < 32 ? y : x) * ifr;
    cs[j].x = cosf(th);
    cs[j].y = sinf(th);
  }
}

// ---- 128x256 GEMM  C = A * B^T  (A: [M][K], B: [N][K], bf16) ----
// K-tile restructure (break LDS-read/MFMA serialization): read ALL 16 operand
// frags (kh0+kh1, distinct regs amA/bnA/amB/bnB) BEFORE one barrier; MFMA-A
// overlaps the read tail (compiler lgkmcnt(8)); MFMA-B has zero read latency
// and overlaps the mid-tile stage issue. 2 barriers/K-tile (was 4).
// vmcnt(3) at tile end retires exactly t+1's kh0+kh1 (audited).
// LDS 96KB: A 2buf x 2kh x 8KB, B 2buf x 2kh x 16KB. Chunk swizzle
// chunk = g ^ ((row>>1)&3), inverse-applied on global src (involution).
// EPI=0: f32 C. EPI=1: QKV epilogue (RoPE q/k, q*=0.125*log2e, V transposed).
template<int EPI>
__global__ __launch_bounds__(512, 2) void gemm8(
    const unsigned short* __restrict__ A,
    const unsigned short* __restrict__ B,
    int K, int N, int NXB,
    float* __restrict__ Cf,
    const float2* __restrict__ cs,
    unsigned short* __restrict__ qw,
    unsigned short* __restrict__ kw,
    unsigned short* __restrict__ vtw)
{
  __shared__ char lds[98304];           // A: 0..32K (2buf x 2kh x 8K), B: 32K..96K
  const int tid = threadIdx.x;
  const int w = tid >> 6, lane = tid & 63;
  const int g = lane >> 4, c0 = lane & 15;
  const int wm = w >> 2, wn = w & 3;    // 2 x 4 wave grid; wave tile 64x64
  const int NT = K >> 6;                // K-tiles of 64

  // XCD-bijective block decode (nwg % 8 == 0)
  const int per = gridDim.x >> 3;
  const int wg = (blockIdx.x & 7) * per + (blockIdx.x >> 3);
  const int by = wg / NXB, bx = wg % NXB;
  const size_t m0 = (size_t)by * 128;
  const size_t n0 = (size_t)bx * 256;

  // staging: ci covers (row=ci>>2, chunk=ci&3) of a [rows][32] half.
  // LDS dest linear; global src chunk = (ci&3) ^ ((row>>1)&3)  [involution]
  const int row0 = tid >> 2;                       // 0..127
  const int xch = (tid & 3) ^ ((tid >> 3) & 3);
  const unsigned short* sA0 = A + (m0 + row0) * K + xch * 8;
  const unsigned short* sB0 = B + (n0 + row0) * K + xch * 8;
  const unsigned short* sB1 = B + (n0 + row0 + 128) * K + xch * 8;
  char* const Ald = lds;
  char* const Bld = lds + 32768;
  const int wb = w * 1024;              // wave-uniform LDS dest base (lane*16 by HW)

  auto stA = [&](int t, int buf, int kh){
    gload_lds16(sA0 + t * 64 + kh * 32, Ald + buf * 16384 + kh * 8192 + wb);
  };
  auto stB = [&](int t, int buf, int kh){
    char* d = Bld + buf * 32768 + kh * 16384 + wb;
    gload_lds16(sB0 + t * 64 + kh * 32, d);
    gload_lds16(sB1 + t * 64 + kh * 32, d + 8192);
  };

  // swizzled read: chunk = g ^ ((row>>1)&3); (row>>1)&3 = (c0>>1)&3 for frag rows
  const int archy = (g ^ ((c0 >> 1) & 3)) << 4;
  auto rdA = [&](int buf, int kh, int mf) -> short8v {
    return *(const short8v*)(Ald + buf * 16384 + kh * 8192 +
                             (wm * 64 + mf * 16 + c0) * 64 + archy);
  };
  auto rdB = [&](int buf, int kh, int nf) -> short8v {
    return *(const short8v*)(Bld + buf * 32768 + kh * 16384 +
                             (wn * 64 + nf * 16 + c0) * 64 + archy);
  };

  floatx4 acc[4][4] = {};

#define BARX() do{ __builtin_amdgcn_s_barrier(); __builtin_amdgcn_sched_barrier(0); }while(0)

  auto tile2 = [&](int t, int buf){
    const int ob = buf ^ 1;
    const int tn1 = (t + 1 < NT) ? t + 1 : NT - 1;
    const int tn2 = (t + 2 < NT) ? t + 2 : NT - 1;
    short8v amA[4], bnA[4], amB[4], bnB[4];
    // batch-read BOTH kh halves into distinct regs (16 ds_read_b128)
    #pragma unroll
    for(int nf = 0; nf < 4; ++nf) bnA[nf] = rdB(buf, 0, nf);
    #pragma unroll
    for(int mf = 0; mf < 4; ++mf) amA[mf] = rdA(buf, 0, mf);
    #pragma unroll
    for(int nf = 0; nf < 4; ++nf) bnB[nf] = rdB(buf, 1, nf);
    #pragma unroll
    for(int mf = 0; mf < 4; ++mf) amB[mf] = rdA(buf, 1, mf);
    // stage t+1 kh1 -> other buf (3 loads)
    stA(tn1, ob, 1); stB(tn1, ob, 1);
    __builtin_amdgcn_sched_barrier(0);
    BARX();
    // MFMA-A: starts once first 8 reads land (compiler lgkmcnt(8)); tail overlaps
    __builtin_amdgcn_s_setprio(1);
    #pragma unroll
    for(int mf = 0; mf < 4; ++mf)
      #pragma unroll
      for(int nf = 0; nf < 4; ++nf)
        acc[mf][nf] = __builtin_amdgcn_mfma_f32_16x16x32_bf16(amA[mf], bnA[nf], acc[mf][nf], 0, 0, 0);
    __builtin_amdgcn_s_setprio(0);
    // mid-stage t+2 kh0 -> this buf (kh0 reads all completed pre-barrier)
    stA(tn2, buf, 0); stB(tn2, buf, 0);
    // MFMA-B: zero read latency
    __builtin_amdgcn_s_setprio(1);
    #pragma unroll
    for(int mf = 0; mf < 4; ++mf)
      #pragma unroll
      for(int nf = 0; nf < 4; ++nf)
        acc[mf][nf] = __builtin_amdgcn_mfma_f32_16x16x32_bf16(amB[mf], bnB[nf], acc[mf][nf], 0, 0, 0);
    __builtin_amdgcn_s_setprio(0);
    // retire t+1's kh0 (leftover) + kh1 (this tile's pre-stage); keep t+2 kh0
    asm volatile("s_waitcnt vmcnt(3)" ::: "memory");
    BARX();
  };

  // prologue: t0 kh0+kh1 + t1 kh0 (9 loads); retire t0's 6, leave t1-kh0 flying
  stA(0, 0, 0); stB(0, 0, 0);
  stA(0, 0, 1); stB(0, 0, 1);
  stA(1, 1, 0); stB(1, 1, 0);
  asm volatile("s_waitcnt vmcnt(3)" ::: "memory");
  BARX();

  for(int t = 0; t < NT; t += 2){ tile2(t, 0); tile2(t + 1, 1); }
  __syncthreads();    // full drain: no dangling gload_lds writes past kernel end
#undef BARX

  // ---- epilogue ---- C-layout: col = c0, row = g*4 + r  [m89-verified]
  if(EPI == 0){
    #pragma unroll
    for(int mf = 0; mf < 4; ++mf){
      size_t mrow = m0 + wm * 64 + mf * 16 + g * 4;
      #pragma unroll
      for(int nf = 0; nf < 4; ++nf){
        size_t n = n0 + wn * 64 + nf * 16 + c0;
        #pragma unroll
        for(int r = 0; r < 4; ++r)
          Cf[(mrow + r) * N + n] = acc[mf][nf][r];
      }
    }
  } else {
    int t = (int)(n0 >> 6) + wn;          // 64-col group: 0..47
    int sect = t % 3, hh = t / 3;         // 0=q,1=k,2=v ; head
    if(sect == 2){
      // V -> V^T [bh][64][1024]
      #pragma unroll
      for(int mf = 0; mf < 4; ++mf){
        size_t m = m0 + wm * 64 + mf * 16 + g * 4;
        int b = (int)(m >> 10); int p = (int)(m & 1023);
        #pragma unroll
        for(int nf = 0; nf < 4; ++nf){
          int d = nf * 16 + c0;
          ushortx4 pk;
          #pragma unroll
          for(int r = 0; r < 4; ++r) pk[r] = (unsigned short)f2bf(acc[mf][nf][r]);
          *(ushortx4*)(vtw + ((size_t)(b * 16 + hh) * 64 + d) * 1024 + p) = pk;
        }
      }
    } else {
      // RoPE: pairs (d, d+32) live in frags (nf, nf+2) of the same thread.
      // Pair-packed dword stores: even lane stores (d,d+1), odd stores (d+31,d+32).
      unsigned short* dst = (sect == 0) ? qw : kw;
      const float qs = (sect == 0) ? 0.18033688011112042f : 1.0f;  // 0.125*log2e
      const int codd = c0 & 1;
      #pragma unroll
      for(int mf = 0; mf < 4; ++mf){
        #pragma unroll
        for(int r = 0; r < 4; ++r){
          size_t m = m0 + wm * 64 + mf * 16 + g * 4 + r;
          int b = (int)(m >> 10); int p = (int)(m & 1023);
          const float2* csr = cs + (size_t)p * 64;
          unsigned short* orow = dst + ((size_t)(b * 16 + hh) * 1024 + p) * 64;
          #pragma unroll
          for(int nf = 0; nf < 2; ++nf){
            int d = nf * 16 + c0;
            float x1 = acc[mf][nf][r], x2 = acc[mf][nf + 2][r];
            float2 cc1 = csr[d], cc2 = csr[d + 32];
            unsigned int u1 = f2bf((x1 * cc1.x - x2 * cc1.y) * qs);  // elem d
            unsigned int u2 = f2bf((x2 * cc2.x + x1 * cc2.y) * qs);  // elem d+32
            unsigned int p1 = (unsigned int)__shfl_xor((int)u1, 1);
            unsigned int p2 = (unsigned int)__shfl_xor((int)u2, 1);
            unsigned int val = codd ? (p2 | (u2 << 16)) : (u1 | (p1 << 16));
            int off = codd ? (d + 31) : d;
            *(unsigned int*)(orow + off) = val;
          }
        }
      }
    }
  }
}

// ---- flash attention v4b: 512 blocks x 512 thr (8 waves, 32 q-rows each) ----
// K/V tiles staged in LDS (shared by 8 waves), double-buffered, prefetched one
// iteration ahead via global_load_lds. XOR-swizzled K/V LDS layout.
// exp2-domain softmax, defer-max, deferred l-reduce, wave-private P buffer.
__global__ __launch_bounds__(512, 4) void attn_kernel(
    const unsigned short* __restrict__ qw,
    const unsigned short* __restrict__ kw,
    const unsigned short* __restrict__ vtw,
    unsigned short* __restrict__ ow)
{
  __shared__ char smem[65536];
  const int tid = threadIdx.x;
  const int w = tid >> 6, lane = tid & 63;
  const int g = lane >> 4, c0 = lane & 15;
  const int bb = blockIdx.x;                  // 0..511
  const int xcd = bb & 7, slot = bb >> 3;
  const int bh = xcd + ((slot >> 2) << 3);
  const int qt = slot & 3;
  const size_t bhoff = (size_t)bh * 1024 * 64;
  const unsigned short* Qb = qw + bhoff;
  const unsigned short* Kb = kw + bhoff;
  const unsigned short* Vb = vtw + bhoff;
  const int q0 = qt * 256 + w * 32;
  char* Pw = smem + 32768 + w * 4096;

  const int srow = tid >> 3;
  const int sjx = ((tid & 7) ^ (srow & 7)) << 3;
  const unsigned short* ksrc = Kb + srow * 64 + sjx;
  const unsigned short* vsrc = Vb + (size_t)srow * 1024 + sjx;
  const int wbase = w * 1024;

  short8v bq[2][2];
  #pragma unroll
  for(int qf = 0; qf < 2; ++qf)
    #pragma unroll
    for(int i = 0; i < 2; ++i)
      bq[qf][i] = *(const short8v*)(Qb + (size_t)(q0 + qf * 16 + c0) * 64 + g * 8 + i * 32);

  floatx4 o[2][4] = {};
  float m_run[2] = {-1e30f, -1e30f};
  float l_part[2] = {0.0f, 0.0f};

  gload_lds16(ksrc, smem + wbase);
  gload_lds16(vsrc, smem + 8192 + wbase);
  __syncthreads();

  int cur = 0;
  for(int kv0 = 0; kv0 < 1024; kv0 += 64){
    char* Ksm = smem + cur * 16384;
    char* Vsm = smem + cur * 16384 + 8192;
    if(kv0 + 64 < 1024){
      char* alt = smem + (cur ^ 1) * 16384;
      gload_lds16(ksrc + (size_t)(kv0 + 64) * 64, alt + wbase);
      gload_lds16(vsrc + kv0 + 64, alt + 8192 + wbase);
    }
    floatx4 st[4][2];
    #pragma unroll
    for(int kf = 0; kf < 4; ++kf){
      const int krow = kf * 16 + c0;
      const char* kr = Ksm + (krow << 7);
      short8v ka0 = *(const short8v*)(kr + (((g    ) ^ (c0 & 7)) << 4));
      short8v ka1 = *(const short8v*)(kr + (((g + 4) ^ (c0 & 7)) << 4));
      #pragma unroll
      for(int qf = 0; qf < 2; ++qf){
        floatx4 z = {};
        z = __builtin_amdgcn_mfma_f32_16x16x32_bf16(ka0, bq[qf][0], z, 0, 0, 0);
        st[kf][qf] = __builtin_amdgcn_mfma_f32_16x16x32_bf16(ka1, bq[qf][1], z, 0, 0, 0);
      }
    }
    float vmax[2];
    #pragma unroll
    for(int qf = 0; qf < 2; ++qf){
      float vm = -1e30f;
      #pragma unroll
      for(int kf = 0; kf < 4; ++kf)
        #pragma unroll
        for(int r = 0; r < 4; ++r) vm = fmaxf(vm, st[kf][qf][r]);
      vm = fmaxf(vm, __shfl_xor(vm, 16));
      vm = fmaxf(vm, __shfl_xor(vm, 32));
      vmax[qf] = vm;
    }
    if(!__all(vmax[0] <= m_run[0] + 8.0f && vmax[1] <= m_run[1] + 8.0f)){
      #pragma unroll
      for(int qf = 0; qf < 2; ++qf){
        float m_new = fmaxf(m_run[qf], vmax[qf]);
        float sc = __builtin_amdgcn_exp2f(m_run[qf] - m_new);
        l_part[qf] *= sc;
        m_run[qf] = m_new;
        float f0 = __shfl(sc, g * 4 + 0);
        float f1 = __shfl(sc, g * 4 + 1);
        float f2 = __shfl(sc, g * 4 + 2);
        float f3 = __shfl(sc, g * 4 + 3);
        #pragma unroll
        for(int nf = 0; nf < 4; ++nf){
          o[qf][nf][0] *= f0; o[qf][nf][1] *= f1; o[qf][nf][2] *= f2; o[qf][nf][3] *= f3;
        }
      }
    }
    #pragma unroll
    for(int qf = 0; qf < 2; ++qf){
      float ps = 0.0f;
      #pragma unroll
      for(int kf = 0; kf < 4; ++kf){
        ushortx4 pk;
        #pragma unroll
        for(int r = 0; r < 4; ++r){
          float e = __builtin_amdgcn_exp2f(st[kf][qf][r] - m_run[qf]);
          ps += e;
          pk[r] = (unsigned short)f2bf(e);
        }
        int byo = (qf << 11) + (c0 << 7) + (kf << 5) + (g << 3);
        byo ^= (c0 & 7) << 4;
        *(ushortx4*)(Pw + byo) = pk;
      }
      l_part[qf] += ps;
    }
    short8v pa[2][2];
    #pragma unroll
    for(int mf = 0; mf < 2; ++mf)
      #pragma unroll
      for(int i = 0; i < 2; ++i){
        int byo = (mf << 11) + (c0 << 7) + (i << 6) + (g << 4);
        byo ^= (c0 & 7) << 4;
        pa[mf][i] = *(const short8v*)(Pw + byo);
      }
    #pragma unroll
    for(int nf = 0; nf < 4; ++nf){
      const int vrow = nf * 16 + c0;
      const char* vr = Vsm + (vrow << 7);
      short8v v0 = *(const short8v*)(vr + (((g    ) ^ (c0 & 7)) << 4));
      short8v v1 = *(const short8v*)(vr + (((g + 4) ^ (c0 & 7)) << 4));
      #pragma unroll
      for(int mf = 0; mf < 2; ++mf){
        o[mf][nf] = __builtin_amdgcn_mfma_f32_16x16x32_bf16(pa[mf][0], v0, o[mf][nf], 0, 0, 0);
        o[mf][nf] = __builtin_amdgcn_mfma_f32_16x16x32_bf16(pa[mf][1], v1, o[mf][nf], 0, 0, 0);
      }
    }
    __syncthreads();
    cur ^= 1;
  }

  const int b = bh >> 4, hh = bh & 15;
  #pragma unroll
  for(int mf = 0; mf < 2; ++mf){
    l_part[mf] += __shfl_xor(l_part[mf], 16);
    l_part[mf] += __shfl_xor(l_part[mf], 32);
    float i0 = 1.0f / __shfl(l_part[mf], g * 4 + 0);
    float i1 = 1.0f / __shfl(l_part[mf], g * 4 + 1);
    float i2 = 1.0f / __shfl(l_part[mf], g * 4 + 2);
    float i3 = 1.0f / __shfl(l_part[mf], g * 4 + 3);
    #pragma unroll
    for(int nf = 0; nf < 4; ++nf){
      o[mf][nf][0] *= i0; o[mf][nf][1] *= i1; o[mf][nf][2] *= i2; o[mf][nf][3] *= i3;
      #pragma unroll
      for(int r = 0; r < 4; ++r){
        size_t row = (size_t)b * 1024 + q0 + mf * 16 + g * 4 + r;
        ow[row * 1024 + hh * 64 + nf * 16 + c0] = (unsigned short)f2bf(o[mf][nf][r]);
      }
    }
  }
}

// ---- workspace layout (bytes) ----
//   bfT    @ 0         16,777,216   tensor bf16 (8192x1024)
//   bfWq   @ 16777216   6,291,456   w_qkv bf16 (3072x1024)
//   bfWp   @ 23068672   2,097,152   w_proj bf16 (1024x1024)
//   cs     @ 25165824     524,288   RoPE table float2 (1024x64)
//   qw     @ 25690112  16,777,216   Q rope'd*scale bf16 [bh][1024][64]
//   kw     @ 42467328  16,777,216   K rope'd bf16 [bh][1024][64]
//   vtw    @ 59244544  16,777,216   V^T bf16 [bh][64][1024]
//   ow     @ 76021760  16,777,216   attn out bf16 [b*n][c]

extern "C" void kernel_launch(void* const* d_in, const int* in_sizes, int n_in,
                              void* d_out, int out_size, void* d_ws, size_t ws_size,
                              hipStream_t stream){
  const float* tensor = (const float*)d_in[0];
  const float* w_qkv  = (const float*)d_in[1];
  const float* w_proj = (const float*)d_in[2];
  char* ws = (char*)d_ws;
  unsigned short* bfT  = (unsigned short*)(ws);
  unsigned short* bfWq = (unsigned short*)(ws + 16777216);
  unsigned short* bfWp = (unsigned short*)(ws + 23068672);
  float2*         cs   = (float2*)        (ws + 25165824);
  unsigned short* qw   = (unsigned short*)(ws + 25690112);
  unsigned short* kw   = (unsigned short*)(ws + 42467328);
  unsigned short* vtw  = (unsigned short*)(ws + 59244544);
  unsigned short* owp  = (unsigned short*)(ws + 76021760);

  // fused convert + RoPE table: 3145728 cvt threads + 65536 cs threads
  prep<<<12544, 256, 0, stream>>>((const floatx4*)tensor, (ushortx4*)bfT,
                                  (const floatx4*)w_qkv,  (ushortx4*)bfWq,
                                  (const floatx4*)w_proj, (ushortx4*)bfWp, cs);

  // QKV: M=8192, N=3072, K=1024 ; grid 64x12 = 768 = 3 even rounds
  gemm8<1><<<768, 512, 0, stream>>>(bfT, bfWq, 1024, 3072, 12,
                                    nullptr, cs, qw, kw, vtw);
  // attention: 512 blocks x 512 threads
  attn_kernel<<<512, 512, 0, stream>>>(qw, kw, vtw, owp);
  // proj: M=8192, N=1024, K=1024 ; grid 64x4 = 256 = 1 even round
  gemm8<0><<<256, 512, 0, stream>>>(owp, bfWp, 1024, 1024, 4,
                                    (float*)d_out, nullptr, nullptr, nullptr, nullptr);
}

// Round 11
// 160.206 us; speedup vs baseline: 1.0060x; 1.0060x over previous
//
#include <hip/hip_runtime.h>

// ---- vector types (ext_vector for [] indexing; avoid HIP name collisions) ----
typedef __attribute__((ext_vector_type(8))) short short8v;      // 8 bf16 (4 VGPR) MFMA frag
typedef __attribute__((ext_vector_type(4))) float floatx4;      // MFMA accum
typedef __attribute__((ext_vector_type(4))) unsigned short ushortx4;

// RNE f32->bf16, 3 VALU ops (values are finite; no NaN path needed)
__device__ __forceinline__ unsigned int f2bf(float f){
  unsigned int u = __float_as_uint(f);
  u += 0x7fffu + ((u >> 16) & 1u);
  return u >> 16;
}

__device__ __forceinline__ void gload_lds16(const void* g, void* l){
  __builtin_amdgcn_global_load_lds((const __attribute__((address_space(1))) void*)g,
                                   (__attribute__((address_space(3))) void*)l, 16, 0, 0);
}

// ---- fused prep: f32->bf16 for tensor/w_qkv/w_proj + RoPE cos/sin table ----
// region boundaries are multiples of 256 -> each block is branch-uniform.
__global__ __launch_bounds__(256) void prep(
    const floatx4* __restrict__ t,  ushortx4* __restrict__ dt,
    const floatx4* __restrict__ wq, ushortx4* __restrict__ dq,
    const floatx4* __restrict__ wp, ushortx4* __restrict__ dp,
    float2* __restrict__ cs)
{
  int i = blockIdx.x * 256 + threadIdx.x;
  if(i < 3145728){
    const floatx4* s; ushortx4* d; int j;
    if(i < 2097152){ s = t;  d = dt; j = i; }
    else if(i < 2883584){ s = wq; d = dq; j = i - 2097152; }
    else { s = wp; d = dp; j = i - 2883584; }
    floatx4 v = s[j];
    ushortx4 o;
    #pragma unroll
    for(int k = 0; k < 4; ++k) o[k] = (unsigned short)f2bf(v[k]);
    d[j] = o;
  } else {
    int j = i - 3145728;              // 0..65535
    int p = j >> 6, dd = j & 63;
    int y = p >> 5, x = p & 31;
    int dm = dd & 31;
    float ifr = powf(10000.0f, -(float)dm * (1.0f / 32.0f));
    float th = (float)(dd < 32 ? y : x) * ifr;
    cs[j].x = cosf(th);
    cs[j].y = sinf(th);
  }
}

// ---- 128x256 GEMM  C = A * B^T  (A: [M][K], B: [N][K], bf16) ----
// Depth-2 pipeline, 3 LDS buffers (144KB, 1 block/CU): at tile t, read all 16
// frags from buf[t%3] and stage ALL of tile t+2 into buf[(t+2)%3] (WAR-free:
// last read at t-1, trailing barrier passed). Tile-end vmcnt(6) retires t+1's
// 6 loads, which were issued a FULL TILE earlier -> staging latency is fully
// hidden (the old mid-tile vmcnt(3) gated on loads issued ~300cyc before).
// One barrier + one counted vmcnt per K-tile. Chunk swizzle: chunk =
// g ^ ((row>>1)&3), inverse-applied on global src (involution; conflicts=0).
// Buffer layout (48KB each): A [kh][128][64B] @0, B [kh][256][64B] @16K.
// EPI=0: f32 C. EPI=1: QKV epilogue (RoPE q/k, q*=0.125*log2e, V transposed).
template<int EPI>
__global__ __launch_bounds__(512, 2) void gemm8(
    const unsigned short* __restrict__ A,
    const unsigned short* __restrict__ B,
    int K, int N, int NXB,
    float* __restrict__ Cf,
    const float2* __restrict__ cs,
    unsigned short* __restrict__ qw,
    unsigned short* __restrict__ kw,
    unsigned short* __restrict__ vtw)
{
  __shared__ char lds[147456];          // 3 x 48KB
  const int tid = threadIdx.x;
  const int w = tid >> 6, lane = tid & 63;
  const int g = lane >> 4, c0 = lane & 15;
  const int wm = w >> 2, wn = w & 3;    // 2 x 4 wave grid; wave tile 64x64
  const int NT = K >> 6;                // K-tiles of 64

  // XCD-bijective block decode (nwg % 8 == 0)
  const int per = gridDim.x >> 3;
  const int wg = (blockIdx.x & 7) * per + (blockIdx.x >> 3);
  const int by = wg / NXB, bx = wg % NXB;
  const size_t m0 = (size_t)by * 128;
  const size_t n0 = (size_t)bx * 256;

  // staging: ci=tid covers (row=tid>>2, chunk=tid&3) of a [128][32] half.
  // LDS dest linear; global src chunk = (tid&3) ^ ((row>>1)&3)  [involution]
  const int row0 = tid >> 2;                       // 0..127
  const int xch = (tid & 3) ^ ((tid >> 3) & 3);
  const unsigned short* sA0 = A + (m0 + row0) * K + xch * 8;
  const unsigned short* sB0 = B + (n0 + row0) * K + xch * 8;
  const unsigned short* sB1 = B + (n0 + row0 + 128) * K + xch * 8;
  const int wb = w * 1024;              // wave-uniform LDS dest base (lane*16 by HW)

  // stage FULL tile t (A kh0,kh1 + B kh0,kh1 = 6 wave-instrs) into buffer bp
  auto stT = [&](int t, char* bp){
    gload_lds16(sA0 + t * 64,      bp + wb);             // A kh0
    gload_lds16(sA0 + t * 64 + 32, bp + 8192 + wb);      // A kh1
    gload_lds16(sB0 + t * 64,      bp + 16384 + wb);     // B kh0 rows 0-127
    gload_lds16(sB1 + t * 64,      bp + 24576 + wb);     // B kh0 rows 128-255
    gload_lds16(sB0 + t * 64 + 32, bp + 32768 + wb);     // B kh1 rows 0-127
    gload_lds16(sB1 + t * 64 + 32, bp + 40960 + wb);     // B kh1 rows 128-255
  };

  // swizzled read: chunk = g ^ ((row>>1)&3); (row>>1)&3 = (c0>>1)&3 for frag rows
  const int archy = (g ^ ((c0 >> 1) & 3)) << 4;
  auto rdA = [&](const char* bp, int kh, int mf) -> short8v {
    return *(const short8v*)(bp + kh * 8192 + (wm * 64 + mf * 16 + c0) * 64 + archy);
  };
  auto rdB = [&](const char* bp, int kh, int nf) -> short8v {
    return *(const short8v*)(bp + 16384 + kh * 16384 + (wn * 64 + nf * 16 + c0) * 64 + archy);
  };

  floatx4 acc[4][4] = {};

  // prologue: stage tiles 0 and 1 (12 loads); retire tile0's 6, leave t1 flying
  stT(0, lds);
  stT(1, lds + 49152);
  asm volatile("s_waitcnt vmcnt(6)" ::: "memory");
  __builtin_amdgcn_s_barrier();
  __builtin_amdgcn_sched_barrier(0);

  char* pa_ = lds;                      // read buffer   (tile t)
  char* pb_ = lds + 49152;              // next tile     (t+1)
  char* pc_ = lds + 98304;              // stage target  (t+2)
  for(int t = 0; t < NT; ++t){
    const int tn2 = (t + 2 < NT) ? t + 2 : NT - 1;  // clamp keeps vmcnt ledger exact
    short8v amA[4], bnA[4], amB[4], bnB[4];
    #pragma unroll
    for(int nf = 0; nf < 4; ++nf) bnA[nf] = rdB(pa_, 0, nf);
    #pragma unroll
    for(int mf = 0; mf < 4; ++mf) amA[mf] = rdA(pa_, 0, mf);
    #pragma unroll
    for(int nf = 0; nf < 4; ++nf) bnB[nf] = rdB(pa_, 1, nf);
    #pragma unroll
    for(int mf = 0; mf < 4; ++mf) amB[mf] = rdA(pa_, 1, mf);
    stT(tn2, pc_);                      // depth-2 prefetch (dead-buffer dup at tail)
    __builtin_amdgcn_sched_barrier(0);  // pin issue region before MFMA block
    __builtin_amdgcn_s_setprio(1);
    #pragma unroll
    for(int mf = 0; mf < 4; ++mf)
      #pragma unroll
      for(int nf = 0; nf < 4; ++nf)
        acc[mf][nf] = __builtin_amdgcn_mfma_f32_16x16x32_bf16(amA[mf], bnA[nf], acc[mf][nf], 0, 0, 0);
    #pragma unroll
    for(int mf = 0; mf < 4; ++mf)
      #pragma unroll
      for(int nf = 0; nf < 4; ++nf)
        acc[mf][nf] = __builtin_amdgcn_mfma_f32_16x16x32_bf16(amB[mf], bnB[nf], acc[mf][nf], 0, 0, 0);
    __builtin_amdgcn_s_setprio(0);
    // retire tile t+1's 6 loads (issued one full tile ago); keep t+2's 6 flying
    asm volatile("s_waitcnt vmcnt(6)" ::: "memory");
    __builtin_amdgcn_s_barrier();       // WAR fence: next tile stages into pa_
    __builtin_amdgcn_sched_barrier(0);
    char* tmp = pa_; pa_ = pb_; pb_ = pc_; pc_ = tmp;
  }
  __syncthreads();    // full drain: no dangling gload_lds writes past kernel end

  // ---- epilogue ---- C-layout: col = c0, row = g*4 + r  [m89-verified]
  if(EPI == 0){
    #pragma unroll
    for(int mf = 0; mf < 4; ++mf){
      size_t mrow = m0 + wm * 64 + mf * 16 + g * 4;
      #pragma unroll
      for(int nf = 0; nf < 4; ++nf){
        size_t n = n0 + wn * 64 + nf * 16 + c0;
        #pragma unroll
        for(int r = 0; r < 4; ++r)
          Cf[(mrow + r) * N + n] = acc[mf][nf][r];
      }
    }
  } else {
    int t = (int)(n0 >> 6) + wn;          // 64-col group: 0..47
    int sect = t % 3, hh = t / 3;         // 0=q,1=k,2=v ; head
    if(sect == 2){
      // V -> V^T [bh][64][1024]
      #pragma unroll
      for(int mf = 0; mf < 4; ++mf){
        size_t m = m0 + wm * 64 + mf * 16 + g * 4;
        int b = (int)(m >> 10); int p = (int)(m & 1023);
        #pragma unroll
        for(int nf = 0; nf < 4; ++nf){
          int d = nf * 16 + c0;
          ushortx4 pk;
          #pragma unroll
          for(int r = 0; r < 4; ++r) pk[r] = (unsigned short)f2bf(acc[mf][nf][r]);
          *(ushortx4*)(vtw + ((size_t)(b * 16 + hh) * 64 + d) * 1024 + p) = pk;
        }
      }
    } else {
      // RoPE: pairs (d, d+32) live in frags (nf, nf+2) of the same thread.
      // Pair-packed dword stores: even lane stores (d,d+1), odd stores (d+31,d+32).
      unsigned short* dst = (sect == 0) ? qw : kw;
      const float qs = (sect == 0) ? 0.18033688011112042f : 1.0f;  // 0.125*log2e
      const int codd = c0 & 1;
      #pragma unroll
      for(int mf = 0; mf < 4; ++mf){
        #pragma unroll
        for(int r = 0; r < 4; ++r){
          size_t m = m0 + wm * 64 + mf * 16 + g * 4 + r;
          int b = (int)(m >> 10); int p = (int)(m & 1023);
          const float2* csr = cs + (size_t)p * 64;
          unsigned short* orow = dst + ((size_t)(b * 16 + hh) * 1024 + p) * 64;
          #pragma unroll
          for(int nf = 0; nf < 2; ++nf){
            int d = nf * 16 + c0;
            float x1 = acc[mf][nf][r], x2 = acc[mf][nf + 2][r];
            float2 cc1 = csr[d], cc2 = csr[d + 32];
            unsigned int u1 = f2bf((x1 * cc1.x - x2 * cc1.y) * qs);  // elem d
            unsigned int u2 = f2bf((x2 * cc2.x + x1 * cc2.y) * qs);  // elem d+32
            unsigned int p1 = (unsigned int)__shfl_xor((int)u1, 1);
            unsigned int p2 = (unsigned int)__shfl_xor((int)u2, 1);
            unsigned int val = codd ? (p2 | (u2 << 16)) : (u1 | (p1 << 16));
            int off = codd ? (d + 31) : d;
            *(unsigned int*)(orow + off) = val;
          }
        }
      }
    }
  }
}

// ---- flash attention v4b: 512 blocks x 512 thr (8 waves, 32 q-rows each) ----
// K/V tiles staged in LDS (shared by 8 waves), double-buffered, prefetched one
// iteration ahead via global_load_lds. XOR-swizzled K/V LDS layout.
// exp2-domain softmax, defer-max, deferred l-reduce, wave-private P buffer.
__global__ __launch_bounds__(512, 4) void attn_kernel(
    const unsigned short* __restrict__ qw,
    const unsigned short* __restrict__ kw,
    const unsigned short* __restrict__ vtw,
    unsigned short* __restrict__ ow)
{
  __shared__ char smem[65536];
  const int tid = threadIdx.x;
  const int w = tid >> 6, lane = tid & 63;
  const int g = lane >> 4, c0 = lane & 15;
  const int bb = blockIdx.x;                  // 0..511
  const int xcd = bb & 7, slot = bb >> 3;
  const int bh = xcd + ((slot >> 2) << 3);
  const int qt = slot & 3;
  const size_t bhoff = (size_t)bh * 1024 * 64;
  const unsigned short* Qb = qw + bhoff;
  const unsigned short* Kb = kw + bhoff;
  const unsigned short* Vb = vtw + bhoff;
  const int q0 = qt * 256 + w * 32;
  char* Pw = smem + 32768 + w * 4096;

  const int srow = tid >> 3;
  const int sjx = ((tid & 7) ^ (srow & 7)) << 3;
  const unsigned short* ksrc = Kb + srow * 64 + sjx;
  const unsigned short* vsrc = Vb + (size_t)srow * 1024 + sjx;
  const int wbase = w * 1024;

  short8v bq[2][2];
  #pragma unroll
  for(int qf = 0; qf < 2; ++qf)
    #pragma unroll
    for(int i = 0; i < 2; ++i)
      bq[qf][i] = *(const short8v*)(Qb + (size_t)(q0 + qf * 16 + c0) * 64 + g * 8 + i * 32);

  floatx4 o[2][4] = {};
  float m_run[2] = {-1e30f, -1e30f};
  float l_part[2] = {0.0f, 0.0f};

  gload_lds16(ksrc, smem + wbase);
  gload_lds16(vsrc, smem + 8192 + wbase);
  __syncthreads();

  int cur = 0;
  for(int kv0 = 0; kv0 < 1024; kv0 += 64){
    char* Ksm = smem + cur * 16384;
    char* Vsm = smem + cur * 16384 + 8192;
    if(kv0 + 64 < 1024){
      char* alt = smem + (cur ^ 1) * 16384;
      gload_lds16(ksrc + (size_t)(kv0 + 64) * 64, alt + wbase);
      gload_lds16(vsrc + kv0 + 64, alt + 8192 + wbase);
    }
    floatx4 st[4][2];
    #pragma unroll
    for(int kf = 0; kf < 4; ++kf){
      const int krow = kf * 16 + c0;
      const char* kr = Ksm + (krow << 7);
      short8v ka0 = *(const short8v*)(kr + (((g    ) ^ (c0 & 7)) << 4));
      short8v ka1 = *(const short8v*)(kr + (((g + 4) ^ (c0 & 7)) << 4));
      #pragma unroll
      for(int qf = 0; qf < 2; ++qf){
        floatx4 z = {};
        z = __builtin_amdgcn_mfma_f32_16x16x32_bf16(ka0, bq[qf][0], z, 0, 0, 0);
        st[kf][qf] = __builtin_amdgcn_mfma_f32_16x16x32_bf16(ka1, bq[qf][1], z, 0, 0, 0);
      }
    }
    float vmax[2];
    #pragma unroll
    for(int qf = 0; qf < 2; ++qf){
      float vm = -1e30f;
      #pragma unroll
      for(int kf = 0; kf < 4; ++kf)
        #pragma unroll
        for(int r = 0; r < 4; ++r) vm = fmaxf(vm, st[kf][qf][r]);
      vm = fmaxf(vm, __shfl_xor(vm, 16));
      vm = fmaxf(vm, __shfl_xor(vm, 32));
      vmax[qf] = vm;
    }
    if(!__all(vmax[0] <= m_run[0] + 8.0f && vmax[1] <= m_run[1] + 8.0f)){
      #pragma unroll
      for(int qf = 0; qf < 2; ++qf){
        float m_new = fmaxf(m_run[qf], vmax[qf]);
        float sc = __builtin_amdgcn_exp2f(m_run[qf] - m_new);
        l_part[qf] *= sc;
        m_run[qf] = m_new;
        float f0 = __shfl(sc, g * 4 + 0);
        float f1 = __shfl(sc, g * 4 + 1);
        float f2 = __shfl(sc, g * 4 + 2);
        float f3 = __shfl(sc, g * 4 + 3);
        #pragma unroll
        for(int nf = 0; nf < 4; ++nf){
          o[qf][nf][0] *= f0; o[qf][nf][1] *= f1; o[qf][nf][2] *= f2; o[qf][nf][3] *= f3;
        }
      }
    }
    #pragma unroll
    for(int qf = 0; qf < 2; ++qf){
      float ps = 0.0f;
      #pragma unroll
      for(int kf = 0; kf < 4; ++kf){
        ushortx4 pk;
        #pragma unroll
        for(int r = 0; r < 4; ++r){
          float e = __builtin_amdgcn_exp2f(st[kf][qf][r] - m_run[qf]);
          ps += e;
          pk[r] = (unsigned short)f2bf(e);
        }
        int byo = (qf << 11) + (c0 << 7) + (kf << 5) + (g << 3);
        byo ^= (c0 & 7) << 4;
        *(ushortx4*)(Pw + byo) = pk;
      }
      l_part[qf] += ps;
    }
    short8v pa[2][2];
    #pragma unroll
    for(int mf = 0; mf < 2; ++mf)
      #pragma unroll
      for(int i = 0; i < 2; ++i){
        int byo = (mf << 11) + (c0 << 7) + (i << 6) + (g << 4);
        byo ^= (c0 & 7) << 4;
        pa[mf][i] = *(const short8v*)(Pw + byo);
      }
    #pragma unroll
    for(int nf = 0; nf < 4; ++nf){
      const int vrow = nf * 16 + c0;
      const char* vr = Vsm + (vrow << 7);
      short8v v0 = *(const short8v*)(vr + (((g    ) ^ (c0 & 7)) << 4));
      short8v v1 = *(const short8v*)(vr + (((g + 4) ^ (c0 & 7)) << 4));
      #pragma unroll
      for(int mf = 0; mf < 2; ++mf){
        o[mf][nf] = __builtin_amdgcn_mfma_f32_16x16x32_bf16(pa[mf][0], v0, o[mf][nf], 0, 0, 0);
        o[mf][nf] = __builtin_amdgcn_mfma_f32_16x16x32_bf16(pa[mf][1], v1, o[mf][nf], 0, 0, 0);
      }
    }
    __syncthreads();
    cur ^= 1;
  }

  const int b = bh >> 4, hh = bh & 15;
  #pragma unroll
  for(int mf = 0; mf < 2; ++mf){
    l_part[mf] += __shfl_xor(l_part[mf], 16);
    l_part[mf] += __shfl_xor(l_part[mf], 32);
    float i0 = 1.0f / __shfl(l_part[mf], g * 4 + 0);
    float i1 = 1.0f / __shfl(l_part[mf], g * 4 + 1);
    float i2 = 1.0f / __shfl(l_part[mf], g * 4 + 2);
    float i3 = 1.0f / __shfl(l_part[mf], g * 4 + 3);
    #pragma unroll
    for(int nf = 0; nf < 4; ++nf){
      o[mf][nf][0] *= i0; o[mf][nf][1] *= i1; o[mf][nf][2] *= i2; o[mf][nf][3] *= i3;
      #pragma unroll
      for(int r = 0; r < 4; ++r){
        size_t row = (size_t)b * 1024 + q0 + mf * 16 + g * 4 + r;
        ow[row * 1024 + hh * 64 + nf * 16 + c0] = (unsigned short)f2bf(o[mf][nf][r]);
      }
    }
  }
}

// ---- workspace layout (bytes) ----
//   bfT    @ 0         16,777,216   tensor bf16 (8192x1024)
//   bfWq   @ 16777216   6,291,456   w_qkv bf16 (3072x1024)
//   bfWp   @ 23068672   2,097,152   w_proj bf16 (1024x1024)
//   cs     @ 25165824     524,288   RoPE table float2 (1024x64)
//   qw     @ 25690112  16,777,216   Q rope'd*scale bf16 [bh][1024][64]
//   kw     @ 42467328  16,777,216   K rope'd bf16 [bh][1024][64]
//   vtw    @ 59244544  16,777,216   V^T bf16 [bh][64][1024]
//   ow     @ 76021760  16,777,216   attn out bf16 [b*n][c]

extern "C" void kernel_launch(void* const* d_in, const int* in_sizes, int n_in,
                              void* d_out, int out_size, void* d_ws, size_t ws_size,
                              hipStream_t stream){
  const float* tensor = (const float*)d_in[0];
  const float* w_qkv  = (const float*)d_in[1];
  const float* w_proj = (const float*)d_in[2];
  char* ws = (char*)d_ws;
  unsigned short* bfT  = (unsigned short*)(ws);
  unsigned short* bfWq = (unsigned short*)(ws + 16777216);
  unsigned short* bfWp = (unsigned short*)(ws + 23068672);
  float2*         cs   = (float2*)        (ws + 25165824);
  unsigned short* qw   = (unsigned short*)(ws + 25690112);
  unsigned short* kw   = (unsigned short*)(ws + 42467328);
  unsigned short* vtw  = (unsigned short*)(ws + 59244544);
  unsigned short* owp  = (unsigned short*)(ws + 76021760);

  // fused convert + RoPE table: 3145728 cvt threads + 65536 cs threads
  prep<<<12544, 256, 0, stream>>>((const floatx4*)tensor, (ushortx4*)bfT,
                                  (const floatx4*)w_qkv,  (ushortx4*)bfWq,
                                  (const floatx4*)w_proj, (ushortx4*)bfWp, cs);

  // QKV: M=8192, N=3072, K=1024 ; grid 64x12 = 768 = 3 even rounds
  gemm8<1><<<768, 512, 0, stream>>>(bfT, bfWq, 1024, 3072, 12,
                                    nullptr, cs, qw, kw, vtw);
  // attention: 512 blocks x 512 threads
  attn_kernel<<<512, 512, 0, stream>>>(qw, kw, vtw, owp);
  // proj: M=8192, N=1024, K=1024 ; grid 64x4 = 256 = 1 even round
  gemm8<0><<<256, 512, 0, stream>>>(owp, bfWp, 1024, 1024, 4,
                                    (float*)d_out, nullptr, nullptr, nullptr, nullptr);
}